// Round 8
// baseline (167.324 us; speedup 1.0000x reference)
//
#include <hip/hip_runtime.h>

#define B_N 16
#define S_LEN 2048
#define D_DIM 128
#define TK 32
#define NPH 16            // phases per key-quarter (4 groups x 16 x 32 keys = 2048)

typedef __attribute__((ext_vector_type(16))) float f32x16;
typedef __attribute__((ext_vector_type(8)))  short short8;
typedef __attribute__((ext_vector_type(4)))  int   i32x4;
typedef const __attribute__((address_space(1))) void* gp1;
typedef __attribute__((address_space(3))) void* sp3;
// DMA: wave-uniform LDS base, HW lands lane L's 16B at base + L*16
#define GLL(g, l) __builtin_amdgcn_global_load_lds((gp1)(const void*)(g), (sp3)(void*)(l), 16, 0, 0)

static __device__ __forceinline__ unsigned short f2bf(float f) {
  unsigned u = __builtin_bit_cast(unsigned, f);
  return (unsigned short)((u + 0x7fffu + ((u >> 16) & 1u)) >> 16);  // RNE
}

// ---------------- prepass: K -> bf16 row-major; V -> bf16 transposed [b][d][s] ----------------
__global__ __launch_bounds__(256)
void prep_kernel(const float* __restrict__ K, const float* __restrict__ V,
                 unsigned short* __restrict__ Kb, unsigned short* __restrict__ VT) {
  __shared__ unsigned short lds[64 * 66];
  int bx = blockIdx.x;
  int t  = threadIdx.x;
  if (bx < 1024) {
    // K convert: 16 elems/thread, fully coalesced, block-strided
#pragma unroll
    for (int rep = 0; rep < 4; ++rep) {
      size_t i = (((size_t)rep * 1024 + bx) * 256 + t) * 4;
      float4 v = *(const float4*)(K + i);
      unsigned lo = (unsigned)f2bf(v.x) | ((unsigned)f2bf(v.y) << 16);
      unsigned hi = (unsigned)f2bf(v.z) | ((unsigned)f2bf(v.w) << 16);
      *(uint2*)(Kb + i) = make_uint2(lo, hi);
    }
  } else {
    // V transpose+convert: 64(s) x 64(d) tile via LDS, float4 both sides
    int bi = bx - 1024;                 // 1024 = 16 b x 32 st x 2 dt
    int b  = bi & 15;
    int st = (bi >> 4) & 31;
    int dt = bi >> 9;
    const float* Vb = V + ((size_t)b * S_LEN + st * 64) * D_DIM + dt * 64;
    unsigned short* VTb = VT + ((size_t)b * D_DIM + dt * 64) * S_LEN + st * 64;
#pragma unroll
    for (int rep = 0; rep < 4; ++rep) {
      int idx = rep * 256 + t;
      int i  = idx >> 4;                // s-local 0..63
      int j4 = (idx & 15) * 4;          // d-local
      float4 v = *(const float4*)(Vb + (size_t)i * D_DIM + j4);
      unsigned lo = (unsigned)f2bf(v.x) | ((unsigned)f2bf(v.y) << 16);
      unsigned hi = (unsigned)f2bf(v.z) | ((unsigned)f2bf(v.w) << 16);
      *(uint2*)&lds[i * 66 + j4] = make_uint2(lo, hi);
    }
    __syncthreads();
#pragma unroll
    for (int rep = 0; rep < 4; ++rep) {
      int idx = rep * 256 + t;
      int dd = idx >> 4;                // d-local 0..63
      int s4 = (idx & 15) * 4;          // s-local
      unsigned short e0 = lds[(s4 + 0) * 66 + dd];
      unsigned short e1 = lds[(s4 + 1) * 66 + dd];
      unsigned short e2 = lds[(s4 + 2) * 66 + dd];
      unsigned short e3 = lds[(s4 + 3) * 66 + dd];
      *(uint2*)(VTb + (size_t)dd * S_LEN + s4) =
          make_uint2((unsigned)e0 | ((unsigned)e1 << 16),
                     (unsigned)e2 | ((unsigned)e3 << 16));
    }
  }
}

// ---------------- main attention: 512 thr x 256 blocks, 64 q-rows/wave, split-K=4 --------
// AI doubled: each wave owns TWO 32-row Q-tiles; every K/V fragment read from LDS feeds
// 2 MFMAs (shared kf/vf) -> LDS traffic per FLOP halved (2 MB/CU vs 4), L2 halved, phase
// count halved (16). T12 softmax unchanged. Depth-2 buffers, vmcnt(0)+1 barrier per phase
// (loads issued a full phase ahead -> drain is free).
__global__ __launch_bounds__(512, 2)
void attn_kernel(const float* __restrict__ Q, const unsigned short* __restrict__ Kb,
                 const unsigned short* __restrict__ VT, float* __restrict__ O) {
  // layout: per group g (4 groups x 32KB): [K0 8K][K1 8K][V0 8K][V1 8K]
  // merge overlay (post-loop): mo[128][128] f32 = 64KB at 0; ml[4][128] f32 at 65536
  __shared__ __align__(16) char smem[131072];

  const int tid  = threadIdx.x;
  const int wave = tid >> 6;            // 0..7
  const int g    = wave >> 1;           // key-quarter group 0..3
  const int w2   = wave & 1;            // q-64-row group within block
  const int lane = tid & 63;
  const int l32  = lane & 31;
  const int half = lane >> 5;

  // XCD swizzle: all 16 q-blocks of one batch land on the same XCD (K/V L2 residency)
  const int i     = blockIdx.x;         // 0..255
  const int b     = (i & 7) * 2 + ((i >> 3) & 1);
  const int qt    = i >> 4;             // 0..15
  const int qbase = qt * 128 + w2 * 64; // this wave's 64 q-rows

  const float* Qb = Q + (size_t)b * S_LEN * D_DIM;
  const unsigned short* Kbb = Kb + (size_t)b * S_LEN * D_DIM;
  const unsigned short* VTb = VT + (size_t)b * D_DIM * S_LEN;

  unsigned short* kb0 = (unsigned short*)(smem + g * 32768);
  unsigned short* vb0 = (unsigned short*)(smem + g * 32768 + 16384);

  // per-wave DMA of one 32-key phase: 4 K-chunks + 4 V-chunks = 8 vmcnt items
  // (2 waves/group cover the 8+8 chunks)
#define ISSUE_PH(tt, buf)                                                          \
  {                                                                                \
    const int T_ = g * NPH + (tt);                                                 \
    _Pragma("unroll")                                                              \
    for (int cc = 0; cc < 4; ++cc) {                                               \
      int c = w2 * 4 + cc;                                                         \
      int rl = 4 * c + (lane >> 4);                                                \
      int lbk = (lane & 15) ^ (rl & 15);                                           \
      GLL(Kbb + (size_t)(T_ * TK + rl) * D_DIM + lbk * 8, kb0 + (buf) * 4096 + c * 512); \
      int dv = 16 * c + (lane >> 2);                                               \
      int lbv = (lane & 3) ^ ((dv >> 1) & 3);                                      \
      GLL(VTb + (size_t)dv * S_LEN + T_ * TK + lbv * 8, vb0 + (buf) * 4096 + c * 512);   \
    }                                                                              \
  }

#define SOFTMAX(saccv, pf0v, pf1v, lsumv)                                          \
  {                                                                                \
    float p_[16];                                                                  \
    _Pragma("unroll")                                                              \
    for (int reg = 0; reg < 16; ++reg) {                                           \
      p_[reg] = exp2f(saccv[reg] * SC);                                            \
      lsumv += p_[reg];                                                            \
    }                                                                              \
    int dw_[8];                                                                    \
    _Pragma("unroll")                                                              \
    for (int i2 = 0; i2 < 8; ++i2)                                                 \
      asm("v_cvt_pk_bf16_f32 %0, %1, %2"                                           \
          : "=v"(dw_[i2]) : "v"(p_[2 * i2]), "v"(p_[2 * i2 + 1]));                 \
    asm("v_permlane32_swap_b32 %0, %1" : "+v"(dw_[0]), "+v"(dw_[2]));              \
    asm("v_permlane32_swap_b32 %0, %1" : "+v"(dw_[1]), "+v"(dw_[3]));              \
    asm("v_permlane32_swap_b32 %0, %1" : "+v"(dw_[4]), "+v"(dw_[6]));              \
    asm("v_permlane32_swap_b32 %0, %1" : "+v"(dw_[5]), "+v"(dw_[7]));              \
    i32x4 f0_ = {dw_[0], dw_[1], dw_[2], dw_[3]};                                  \
    i32x4 f1_ = {dw_[4], dw_[5], dw_[6], dw_[7]};                                  \
    pf0v = __builtin_bit_cast(short8, f0_);                                        \
    pf1v = __builtin_bit_cast(short8, f1_);                                        \
  }

  // ---- Q B-frags for both 32-row tiles (A: rows qbase+l32, B: qbase+32+l32) ----
  short8 qaA[8], qaB[8];
  {
    const float* qpA = Qb + (size_t)(qbase + l32) * D_DIM + half * 8;
    const float* qpB = Qb + (size_t)(qbase + 32 + l32) * D_DIM + half * 8;
#pragma unroll
    for (int ks = 0; ks < 8; ++ks) {
      float4 a0 = *(const float4*)(qpA + ks * 16);
      float4 a1 = *(const float4*)(qpA + ks * 16 + 4);
      short8 f;
      f[0] = (short)f2bf(a0.x); f[1] = (short)f2bf(a0.y);
      f[2] = (short)f2bf(a0.z); f[3] = (short)f2bf(a0.w);
      f[4] = (short)f2bf(a1.x); f[5] = (short)f2bf(a1.y);
      f[6] = (short)f2bf(a1.z); f[7] = (short)f2bf(a1.w);
      qaA[ks] = f;
      float4 b0 = *(const float4*)(qpB + ks * 16);
      float4 b1 = *(const float4*)(qpB + ks * 16 + 4);
      short8 h;
      h[0] = (short)f2bf(b0.x); h[1] = (short)f2bf(b0.y);
      h[2] = (short)f2bf(b0.z); h[3] = (short)f2bf(b0.w);
      h[4] = (short)f2bf(b1.x); h[5] = (short)f2bf(b1.y);
      h[6] = (short)f2bf(b1.z); h[7] = (short)f2bf(b1.w);
      qaB[ks] = h;
    }
  }

  // ---- prologue: phase 0 in flight ----
  ISSUE_PH(0, 0)

  const f32x16 zf16 = {0.f,0.f,0.f,0.f,0.f,0.f,0.f,0.f,0.f,0.f,0.f,0.f,0.f,0.f,0.f,0.f};
  f32x16 oA[4], oB[4];
  float lsumA = 0.f, lsumB = 0.f;
#pragma unroll
  for (int dt = 0; dt < 4; ++dt) { oA[dt] = zf16; oB[dt] = zf16; }

  const float SC = 0.08838834764831845f * 1.4426950408889634f; // 1/sqrt(128)*log2(e)

  for (int t = 0; t < NPH; ++t) {
    // phase-t loads were issued a full compute phase ago -> drain is ~free
    asm volatile("s_waitcnt vmcnt(0)" ::: "memory");
    __builtin_amdgcn_s_barrier();   // all waves' chunks landed; buf (t+1)&1 reads done

    if (t + 1 < NPH) ISSUE_PH(t + 1, (t + 1) & 1)   // flies during compute(t)

    const unsigned short* kbc = kb0 + (t & 1) * 4096;
    const unsigned short* vbc = vb0 + (t & 1) * 4096;

    // ---- S^T = K Q^T for BOTH q-tiles, shared kf (1 LDS read -> 2 MFMAs) ----
    f32x16 sA = zf16, sB = zf16;
#pragma unroll
    for (int ks = 0; ks < 8; ++ks) {
      int pk = (ks * 2 + half) ^ (l32 & 15);
      short8 kf = *(const short8*)&kbc[l32 * D_DIM + pk * 8];
      sA = __builtin_amdgcn_mfma_f32_32x32x16_bf16(kf, qaA[ks], sA, 0, 0, 0);
      sB = __builtin_amdgcn_mfma_f32_32x32x16_bf16(kf, qaB[ks], sB, 0, 0, 0);
    }

    short8 pfA0, pfA1, pfB0, pfB1;
    SOFTMAX(sA, pfA0, pfA1, lsumA)
    SOFTMAX(sB, pfB0, pfB1, lsumB)

    // ---- O += P V for both tiles, shared vf ----
#pragma unroll
    for (int ks2 = 0; ks2 < 2; ++ks2) {
#pragma unroll
      for (int dt = 0; dt < 4; ++dt) {
        int dv = dt * 32 + l32;
        int pv = (ks2 * 2 + half) ^ ((dv >> 1) & 3);
        short8 vf = *(const short8*)&vbc[dv * TK + pv * 8];
        if (ks2 == 0) {
          oA[dt] = __builtin_amdgcn_mfma_f32_32x32x16_bf16(pfA0, vf, oA[dt], 0, 0, 0);
          oB[dt] = __builtin_amdgcn_mfma_f32_32x32x16_bf16(pfB0, vf, oB[dt], 0, 0, 0);
        } else {
          oA[dt] = __builtin_amdgcn_mfma_f32_32x32x16_bf16(pfA1, vf, oA[dt], 0, 0, 0);
          oB[dt] = __builtin_amdgcn_mfma_f32_32x32x16_bf16(pfB1, vf, oB[dt], 0, 0, 0);
        }
      }
    }
  }
#undef ISSUE_PH
#undef SOFTMAX

  // ---- combine halves: lane l32 holds full key-quarter row sum ----
  lsumA += __shfl_xor(lsumA, 32);
  lsumB += __shfl_xor(lsumB, 32);

  // ---- split-K=4 merge: 3 rounds through 64KB overlay; lsum table up front ----
  __syncthreads();   // all main-loop LDS traffic done
  float* mo = (float*)smem;                  // [128][128] f32
  float* ml = (float*)(smem + 65536);        // [4][128]
  if (half == 0) {
    ml[g * 128 + w2 * 64 + l32]      = lsumA;
    ml[g * 128 + w2 * 64 + 32 + l32] = lsumB;
  }
#pragma unroll
  for (int r = 1; r < 4; ++r) {
    if (g == r) {
#pragma unroll
      for (int reg = 0; reg < 16; ++reg) {
        int row = (reg & 3) + 8 * (reg >> 2) + 4 * half;
#pragma unroll
        for (int dt = 0; dt < 4; ++dt) {
          mo[(w2 * 64 + row) * 128 + dt * 32 + l32]      = oA[dt][reg];
          mo[(w2 * 64 + 32 + row) * 128 + dt * 32 + l32] = oB[dt][reg];
        }
      }
    }
    __syncthreads();
    if (g == 0) {
#pragma unroll
      for (int reg = 0; reg < 16; ++reg) {
        int row = (reg & 3) + 8 * (reg >> 2) + 4 * half;
#pragma unroll
        for (int dt = 0; dt < 4; ++dt) {
          oA[dt][reg] += mo[(w2 * 64 + row) * 128 + dt * 32 + l32];
          oB[dt][reg] += mo[(w2 * 64 + 32 + row) * 128 + dt * 32 + l32];
        }
      }
    }
    __syncthreads();
  }

  if (g == 0) {
    float* Ob = O + (size_t)b * S_LEN * D_DIM;
#pragma unroll
    for (int reg = 0; reg < 16; ++reg) {
      int row = (reg & 3) + 8 * (reg >> 2) + 4 * half;
      int rA = w2 * 64 + row;
      int rB = w2 * 64 + 32 + row;
      float linvA = 1.f / (ml[rA] + ml[128 + rA] + ml[256 + rA] + ml[384 + rA]);
      float linvB = 1.f / (ml[rB] + ml[128 + rB] + ml[256 + rB] + ml[384 + rB]);
#pragma unroll
      for (int dt = 0; dt < 4; ++dt) {
        Ob[(size_t)(qt * 128 + rA) * D_DIM + dt * 32 + l32] = oA[dt][reg] * linvA;
        Ob[(size_t)(qt * 128 + rB) * D_DIM + dt * 32 + l32] = oB[dt][reg] * linvB;
      }
    }
  }
}

extern "C" void kernel_launch(void* const* d_in, const int* in_sizes, int n_in,
                              void* d_out, int out_size, void* d_ws, size_t ws_size,
                              hipStream_t stream) {
  const float* Q = (const float*)d_in[0];
  const float* K = (const float*)d_in[1];
  const float* V = (const float*)d_in[2];
  float* O = (float*)d_out;
  unsigned short* Kb = (unsigned short*)d_ws;                       // 8.4 MB
  unsigned short* VT = Kb + (size_t)B_N * S_LEN * D_DIM;            // 8.4 MB
  prep_kernel<<<dim3(1024 + 1024), dim3(256), 0, stream>>>(K, V, Kb, VT);
  attn_kernel<<<dim3(256), dim3(512), 0, stream>>>(Q, Kb, VT, O);
}